// Round 2
// baseline (546.221 us; speedup 1.0000x reference)
//
#include <hip/hip_runtime.h>

typedef unsigned int u32;
typedef __attribute__((ext_vector_type(8))) short short8;   // 8 x bf16 MFMA frag
typedef __attribute__((ext_vector_type(4))) float f32x4;

__device__ __forceinline__ unsigned short f2bf(float f){
  u32 u = __builtin_bit_cast(u32, f);
  u = u + 0x7fffu + ((u >> 16) & 1u);           // RNE; inputs are finite
  return (unsigned short)(u >> 16);
}
__device__ __forceinline__ float bf2f(unsigned short h){
  return __builtin_bit_cast(float, ((u32)h) << 16);
}

// ---------------------------------------------------------------------------
// K0: pack w_conv [64][64][3][3] f32 -> bf16 fragments, layout
//     Bp[tap][chunk][t][lane][i]  (tap=ki*3+kj, chunk=K-half, t=co/16)
//     lane l elem i <-> B[k = chunk*32 + (l>>4)*8 + i][co = t*16 + (l&15)]
// ---------------------------------------------------------------------------
__global__ __launch_bounds__(256) void k_pack_b(const float* __restrict__ w_conv,
                                                unsigned short* __restrict__ Bp){
  int idx = blockIdx.x*256 + threadIdx.x;       // 36864 total
  if (idx >= 9*2*4*64*8) return;
  int i    = idx & 7;
  int lane = (idx >> 3) & 63;
  int t    = (idx >> 9) & 3;
  int chunk= (idx >> 11) & 1;
  int tap  = idx >> 12;
  int co = t*16 + (lane & 15);
  int c  = chunk*32 + (lane >> 4)*8 + i;
  int ki = tap/3, kj = tap%3;
  Bp[idx] = f2bf(w_conv[((co*64 + c)*3 + ki)*3 + kj]);
}

// ---------------------------------------------------------------------------
// K1: transpose x NCHW f32 -> NHWC bf16  (64px x 64ch per block)
// ---------------------------------------------------------------------------
__global__ __launch_bounds__(256) void k_transpose(const float* __restrict__ x,
                                                   unsigned short* __restrict__ xn){
  __shared__ float tile[64][65];
  int n = blockIdx.y, pix0 = blockIdx.x*64;
  int tid = threadIdx.x, lane = tid & 63, grp = tid >> 6;
  #pragma unroll
  for (int k = 0; k < 16; k++){
    int c = k*4 + grp;
    tile[c][lane] = x[(n*64 + c)*65536 + pix0 + lane];
  }
  __syncthreads();
  #pragma unroll
  for (int k = 0; k < 16; k++){
    int p = k*4 + grp;
    xn[(n*65536 + pix0 + p)*64 + lane] = f2bf(tile[lane][p]);
  }
}

// ---------------------------------------------------------------------------
// K2: offset conv (fp32, 5x5, pad 2, 64->2) + grid coord build.
//     tile: 64 (j, lanes) x 16 (i); 4 groups of 4 rows; 5-row sliding window.
//     PRECISION-CRITICAL: coords amplified by W/2=128 -> stay fp32.
// ---------------------------------------------------------------------------
__global__ __launch_bounds__(256,3) void k_offset(const float* __restrict__ x,
                                                  const float* __restrict__ w_def,
                                                  const float* __restrict__ b_def,
                                                  float2* __restrict__ gridc){
  __shared__ float xt[20][72];
  int n = blockIdx.z, i0 = blockIdx.y*16, j0 = blockIdx.x*64;
  int tid = threadIdx.x, lane = tid & 63, g = tid >> 6;
  float acc0[4] = {0.f,0.f,0.f,0.f}, acc1[4] = {0.f,0.f,0.f,0.f};

  for (int c = 0; c < 64; c++){
    __syncthreads();
    const float* xp = x + (n*64 + c)*65536;
    for (int u = tid; u < 20*68; u += 256){
      int r = u/68, col = u%68;
      int gi = i0 - 2 + r, gj = j0 - 2 + col;
      float v = 0.f;
      if (gi >= 0 && gi < 256 && gj >= 0 && gj < 256) v = xp[gi*256 + gj];
      xt[r][col] = v;
    }
    __syncthreads();

    // uniform weight loads -> scalar regs
    float w0[25], w1[25];
    const float* wp0 = w_def + c*25;
    const float* wp1 = w_def + 1600 + c*25;
    #pragma unroll
    for (int t = 0; t < 25; t++){ w0[t] = wp0[t]; w1[t] = wp1[t]; }

    int rbase = g*4;
    float win[5][5];
    #pragma unroll
    for (int rr = 0; rr < 4; rr++)
      #pragma unroll
      for (int kj = 0; kj < 5; kj++) win[rr][kj] = xt[rbase+rr][lane+kj];

    #pragma unroll
    for (int s = 0; s < 4; s++){
      #pragma unroll
      for (int kj = 0; kj < 5; kj++) win[4][kj] = xt[rbase+s+4][lane+kj];
      float a0 = acc0[s], a1 = acc1[s];
      #pragma unroll
      for (int ki = 0; ki < 5; ki++)
        #pragma unroll
        for (int kj = 0; kj < 5; kj++){
          float v = win[ki][kj];
          a0 = fmaf(v, w0[ki*5+kj], a0);
          a1 = fmaf(v, w1[ki*5+kj], a1);
        }
      acc0[s] = a0; acc1[s] = a1;
      #pragma unroll
      for (int ki = 0; ki < 4; ki++)
        #pragma unroll
        for (int kj = 0; kj < 5; kj++) win[ki][kj] = win[ki+1][kj];
    }
  }

  float bd0 = b_def[0], bd1 = b_def[1];
  #pragma unroll
  for (int s = 0; s < 4; s++){
    int i = i0 + g*4 + s, j = j0 + lane;
    // grid[...,0] = off0 + linspace(-1,1,H)[i] (ROW), grid[...,1] = off1 + lin[j] (COL)
    float gx = acc0[s] + bd0 + (-1.0f + (2.0f/255.0f)*(float)i);
    float gy = acc1[s] + bd1 + (-1.0f + (2.0f/255.0f)*(float)j);
    float ix = ((gx + 1.0f)*256.0f - 1.0f)*0.5f;   // width coord
    float iy = ((gy + 1.0f)*256.0f - 1.0f)*0.5f;   // height coord
    gridc[(n*256 + i)*256 + j] = make_float2(ix, iy);
  }
}

// ---------------------------------------------------------------------------
// K3: bilinear sample, zeros padding. One wave = 64 channels of one pixel;
//     each corner = one coalesced 128B bf16 load from NHWC.
// ---------------------------------------------------------------------------
__global__ __launch_bounds__(256) void k_sample(const unsigned short* __restrict__ xn,
                                                const float2* __restrict__ gridc,
                                                unsigned short* __restrict__ xs){
  int n = blockIdx.z, i0 = blockIdx.y*16, j0 = blockIdx.x*16;
  int tid = threadIdx.x, w = tid >> 6, lane = tid & 63;
  for (int s = 0; s < 4; s++){
    int i = i0 + w*4 + s;
    int rowbase = (n<<16) + (i<<8);
    #pragma unroll 2
    for (int j1 = 0; j1 < 16; j1++){
      int j = j0 + j1;
      float2 g = gridc[rowbase + j];
      float ix = g.x, iy = g.y;
      float x0f = floorf(ix), y0f = floorf(iy);
      float fx = ix - x0f, fy = iy - y0f;
      int x0 = (int)x0f, y0 = (int)y0f;
      int x1 = x0 + 1, y1 = y0 + 1;
      float m00 = ((x0>=0)&(x0<256)&(y0>=0)&(y0<256)) ? 1.f : 0.f;
      float m01 = ((x0>=0)&(x0<256)&(y1>=0)&(y1<256)) ? 1.f : 0.f;
      float m10 = ((x1>=0)&(x1<256)&(y0>=0)&(y0<256)) ? 1.f : 0.f;
      float m11 = ((x1>=0)&(x1<256)&(y1>=0)&(y1<256)) ? 1.f : 0.f;
      int x0c = x0 < 0 ? 0 : (x0 > 255 ? 255 : x0);
      int x1c = x1 < 0 ? 0 : (x1 > 255 ? 255 : x1);
      int y0c = y0 < 0 ? 0 : (y0 > 255 ? 255 : y0);
      int y1c = y1 < 0 ? 0 : (y1 > 255 ? 255 : y1);
      int nb = (n<<16);
      float v00 = bf2f(xn[((nb + (y0c<<8) + x0c)<<6) + lane]) * m00;
      float v01 = bf2f(xn[((nb + (y1c<<8) + x0c)<<6) + lane]) * m01;
      float v10 = bf2f(xn[((nb + (y0c<<8) + x1c)<<6) + lane]) * m10;
      float v11 = bf2f(xn[((nb + (y1c<<8) + x1c)<<6) + lane]) * m11;
      float r = (1.f-fx)*((1.f-fy)*v00 + fy*v01) + fx*((1.f-fy)*v10 + fy*v11);
      xs[((rowbase + j)<<6) + lane] = f2bf(r);
    }
  }
}

// ---------------------------------------------------------------------------
// K4: 3x3 conv 64->64 as implicit GEMM, MFMA 16x16x32 bf16.
//     Block: 16x16 px tile (M=256) x Cout=64 (N). K=9 taps x 64c, A-tile
//     (18x18 px, XOR-swizzled) fully LDS-resident; B staged per-ki (24 KB).
//     4 waves, each 4Mx4N 16x16 tiles. Output transposed back to NCHW.
// ---------------------------------------------------------------------------
__global__ __launch_bounds__(256,2) void k_conv2(const unsigned short* __restrict__ xs,
                                                 const unsigned short* __restrict__ Bp,
                                                 const float* __restrict__ b_conv,
                                                 float* __restrict__ out){
  __shared__ unsigned char Al[324*128];     // 41472 B, swizzled
  __shared__ unsigned char Bl[24576];       // 3 taps worth of B frags
  int n = blockIdx.z, i0 = blockIdx.y*16, j0 = blockIdx.x*16;
  int tid = threadIdx.x, w = tid >> 6, l = tid & 63;

  // stage A: pixels (i0-1..i0+16) x (j0-1..j0+16), 8 x 16B chunks each
  const uint4* xs4 = (const uint4*)xs;
  for (int u = tid; u < 324*8; u += 256){
    int p = u >> 3, q = u & 7;
    int rr = p/18, cc = p%18;
    int gi = i0 - 1 + rr, gj = j0 - 1 + cc;
    uint4 v = make_uint4(0u,0u,0u,0u);
    if (gi >= 0 && gi < 256 && gj >= 0 && gj < 256)
      v = xs4[((n<<16) + (gi<<8) + gj)*8 + q];
    int byte = (p*128 + q*16) ^ ((p & 7) << 4);
    *(uint4*)(Al + byte) = v;
  }

  f32x4 zero = {0.f,0.f,0.f,0.f};
  f32x4 acc[4][4];
  #pragma unroll
  for (int m = 0; m < 4; m++)
    #pragma unroll
    for (int t = 0; t < 4; t++) acc[m][t] = zero;

  #pragma unroll
  for (int ki = 0; ki < 3; ki++){
    __syncthreads();                         // prev B consumed (covers A 1st iter)
    { // stage B slice for this ki (1536 uint4)
      const uint4* src = (const uint4*)(Bp + ki*12288);
      uint4* dst = (uint4*)Bl;
      #pragma unroll
      for (int u = 0; u < 6; u++) dst[tid + 256*u] = src[tid + 256*u];
    }
    __syncthreads();
    #pragma unroll
    for (int kj = 0; kj < 3; kj++)
      #pragma unroll
      for (int ch = 0; ch < 2; ch++){
        short8 a[4];
        #pragma unroll
        for (int m = 0; m < 4; m++){
          int p = (w*4 + m + ki)*18 + (l & 15) + kj;
          int byte = (p*128 + ch*64 + ((l >> 4) << 4)) ^ ((p & 7) << 4);
          a[m] = *(const short8*)(Al + byte);
        }
        #pragma unroll
        for (int t = 0; t < 4; t++){
          short8 b = *(const short8*)(Bl + (((kj*2 + ch)*4 + t)*64 + l)*16);
          #pragma unroll
          for (int m = 0; m < 4; m++)
            acc[m][t] = __builtin_amdgcn_mfma_f32_16x16x32_bf16(a[m], b, acc[m][t], 0, 0, 0);
        }
      }
  }

  // epilogue: D lane map: co = t*16 + (l&15), pixel col = (l>>4)*4 + i
  int colp0 = (l >> 4) * 4;
  #pragma unroll
  for (int t = 0; t < 4; t++){
    int co = t*16 + (l & 15);
    float bias = b_conv[co];
    #pragma unroll
    for (int m = 0; m < 4; m++){
      int r = w*4 + m;
      f32x4 v = acc[m][t];
      v[0] += bias; v[1] += bias; v[2] += bias; v[3] += bias;
      *(f32x4*)(&out[(((n*64 + co)<<8) + i0 + r)*256 + j0 + colp0]) = v;
    }
  }
}

// ---------------------------------------------------------------------------
extern "C" void kernel_launch(void* const* d_in, const int* in_sizes, int n_in,
                              void* d_out, int out_size, void* d_ws, size_t ws_size,
                              hipStream_t stream) {
  const float* x      = (const float*)d_in[0];   // [8,64,256,256]
  const float* w_def  = (const float*)d_in[1];   // [2,64,5,5]
  const float* b_def  = (const float*)d_in[2];   // [2]
  const float* w_conv = (const float*)d_in[3];   // [64,64,3,3]
  const float* b_conv = (const float*)d_in[4];   // [64]
  float* out = (float*)d_out;                    // [8,64,256,256]

  // ws layout (138.5 MB): xn bf16 | xs bf16 | gridc f32x2 | Bp bf16
  unsigned char* ws = (unsigned char*)d_ws;
  unsigned short* xn    = (unsigned short*)(ws);
  unsigned short* xsamp = (unsigned short*)(ws + 67108864);
  float2*         gridc = (float2*)(ws + 134217728);
  unsigned short* Bp    = (unsigned short*)(ws + 138412032);

  k_pack_b   <<<144, 256, 0, stream>>>(w_conv, Bp);
  k_transpose<<<dim3(1024, 8), 256, 0, stream>>>(x, xn);
  k_offset   <<<dim3(4, 16, 8), 256, 0, stream>>>(x, w_def, b_def, gridc);
  k_sample   <<<dim3(16, 16, 8), 256, 0, stream>>>(xn, gridc, xsamp);
  k_conv2    <<<dim3(16, 16, 8), 256, 0, stream>>>(xsamp, Bp, b_conv, out);
}

// Round 4
// 527.140 us; speedup vs baseline: 1.0362x; 1.0362x over previous
//
#include <hip/hip_runtime.h>

typedef unsigned int u32;
typedef __attribute__((ext_vector_type(8))) short short8;   // 8 x bf16 MFMA frag
typedef __attribute__((ext_vector_type(4))) float f32x4;

__device__ __forceinline__ unsigned short f2bf(float f){
  u32 u = __builtin_bit_cast(u32, f);
  u = u + 0x7fffu + ((u >> 16) & 1u);           // RNE; inputs are finite
  return (unsigned short)(u >> 16);
}
__device__ __forceinline__ float bf2f(unsigned short h){
  return __builtin_bit_cast(float, ((u32)h) << 16);
}

// ---------------------------------------------------------------------------
// K0: pack w_conv [64][64][3][3] f32 -> bf16 fragments, layout
//     Bp[tap][chunk][t][lane][i]  (tap=ki*3+kj, chunk=K-half, t=co/16)
//     lane l elem i <-> B[k = chunk*32 + (l>>4)*8 + i][co = t*16 + (l&15)]
// ---------------------------------------------------------------------------
__global__ __launch_bounds__(256) void k_pack_b(const float* __restrict__ w_conv,
                                                unsigned short* __restrict__ Bp){
  int idx = blockIdx.x*256 + threadIdx.x;       // 36864 total
  if (idx >= 9*2*4*64*8) return;
  int i    = idx & 7;
  int lane = (idx >> 3) & 63;
  int t    = (idx >> 9) & 3;
  int chunk= (idx >> 11) & 1;
  int tap  = idx >> 12;
  int co = t*16 + (lane & 15);
  int c  = chunk*32 + (lane >> 4)*8 + i;
  int ki = tap/3, kj = tap%3;
  Bp[idx] = f2bf(w_conv[((co*64 + c)*3 + ki)*3 + kj]);
}

// ---------------------------------------------------------------------------
// K1: transpose x NCHW f32 -> NHWC bf16  (64px x 64ch per block)
// ---------------------------------------------------------------------------
__global__ __launch_bounds__(256) void k_transpose(const float* __restrict__ x,
                                                   unsigned short* __restrict__ xn){
  __shared__ float tile[64][65];
  int n = blockIdx.y, pix0 = blockIdx.x*64;
  int tid = threadIdx.x, lane = tid & 63, grp = tid >> 6;
  #pragma unroll
  for (int k = 0; k < 16; k++){
    int c = k*4 + grp;
    tile[c][lane] = x[(n*64 + c)*65536 + pix0 + lane];
  }
  __syncthreads();
  #pragma unroll
  for (int k = 0; k < 16; k++){
    int p = k*4 + grp;
    xn[(n*65536 + pix0 + p)*64 + lane] = f2bf(tile[lane][p]);
  }
}

// ---------------------------------------------------------------------------
// K2: offset conv (fp32, 5x5, pad 2, 64->2) + grid coord build.
//     Barrier-free main loop. 4 waves x 16 private channels each,
//     register accumulation, direct-global row-streamed windows (L1 serves
//     the 5x kj overlap), s_load weights via readfirstlane(wave-id).
//     One LDS reduction + 1 barrier at the end. Coords stay fp32.
// ---------------------------------------------------------------------------
__global__ __launch_bounds__(256) void k_offset(const float* __restrict__ x,
                                                const float* __restrict__ w_def,
                                                const float* __restrict__ b_def,
                                                float2* __restrict__ gridc){
  __shared__ float red[4][8][2][64];            // 16 KB
  int n = blockIdx.z, i0 = blockIdx.y*8, j0 = blockIdx.x*64;
  int tid = threadIdx.x, lane = tid & 63;
  int w = __builtin_amdgcn_readfirstlane(tid >> 6);   // SGPR wave id
  int j = j0 + lane;

  int jc[5]; float cm[5];
  #pragma unroll
  for (int kj = 0; kj < 5; kj++){
    int cj = j - 2 + kj;
    cm[kj] = (cj >= 0 && cj < 256) ? 1.f : 0.f;
    jc[kj] = cj < 0 ? 0 : (cj > 255 ? 255 : cj);
  }
  float a0[8], a1[8];
  #pragma unroll
  for (int s = 0; s < 8; s++){ a0[s] = 0.f; a1[s] = 0.f; }

  for (int cc = 0; cc < 16; cc++){
    int c = (w << 4) + cc;
    const float* xp  = x + ((n << 6) + c)*65536;
    const float* wq0 = w_def + c*25;
    const float* wq1 = w_def + 1600 + c*25;
    float w0[25], w1[25];
    #pragma unroll
    for (int t = 0; t < 25; t++){ w0[t] = wq0[t]; w1[t] = wq1[t]; }

    #pragma unroll
    for (int r = 0; r < 12; r++){               // input rows i0-2 .. i0+9
      int gi = i0 - 2 + r;
      if (gi < 0 || gi > 255) continue;         // wave-uniform
      float win[5];
      #pragma unroll
      for (int kj = 0; kj < 5; kj++) win[kj] = xp[(gi << 8) + jc[kj]] * cm[kj];
      #pragma unroll
      for (int ki = 0; ki < 5; ki++){
        int s = r - ki;
        if (s < 0 || s > 7) continue;           // compile-time after unroll
        #pragma unroll
        for (int kj = 0; kj < 5; kj++){
          a0[s] = fmaf(win[kj], w0[ki*5+kj], a0[s]);
          a1[s] = fmaf(win[kj], w1[ki*5+kj], a1[s]);
        }
      }
    }
  }

  #pragma unroll
  for (int s = 0; s < 8; s++){ red[w][s][0][lane] = a0[s]; red[w][s][1][lane] = a1[s]; }
  __syncthreads();

  float bd0 = b_def[0], bd1 = b_def[1];
  #pragma unroll
  for (int v = 0; v < 2; v++){
    int p = tid + (v << 8);                     // 0..511 = 8 rows x 64 cols
    int s = p >> 6, ln = p & 63;
    float s0 = red[0][s][0][ln] + red[1][s][0][ln] + red[2][s][0][ln] + red[3][s][0][ln];
    float s1 = red[0][s][1][ln] + red[1][s][1][ln] + red[2][s][1][ln] + red[3][s][1][ln];
    int i = i0 + s, jj = j0 + ln;
    // grid[...,0] = off0 + linspace(-1,1,H)[i] (ROW), grid[...,1] = off1 + lin[j] (COL)
    float gx = s0 + bd0 + (-1.0f + (2.0f/255.0f)*(float)i);
    float gy = s1 + bd1 + (-1.0f + (2.0f/255.0f)*(float)jj);
    float ix = ((gx + 1.0f)*256.0f - 1.0f)*0.5f;   // width coord
    float iy = ((gy + 1.0f)*256.0f - 1.0f)*0.5f;   // height coord
    gridc[((n << 8) + i)*256 + jj] = make_float2(ix, iy);
  }
}

// ---------------------------------------------------------------------------
// K3: bilinear sample, zeros padding. One wave = 64 channels of one pixel;
//     each corner = one coalesced 128B bf16 load from NHWC.
// ---------------------------------------------------------------------------
__global__ __launch_bounds__(256) void k_sample(const unsigned short* __restrict__ xn,
                                                const float2* __restrict__ gridc,
                                                unsigned short* __restrict__ xs){
  int n = blockIdx.z, i0 = blockIdx.y*16, j0 = blockIdx.x*16;
  int tid = threadIdx.x, w = tid >> 6, lane = tid & 63;
  for (int s = 0; s < 4; s++){
    int i = i0 + w*4 + s;
    int rowbase = (n<<16) + (i<<8);
    #pragma unroll 2
    for (int j1 = 0; j1 < 16; j1++){
      int j = j0 + j1;
      float2 g = gridc[rowbase + j];
      float ix = g.x, iy = g.y;
      float x0f = floorf(ix), y0f = floorf(iy);
      float fx = ix - x0f, fy = iy - y0f;
      int x0 = (int)x0f, y0 = (int)y0f;
      int x1 = x0 + 1, y1 = y0 + 1;
      float m00 = ((x0>=0)&(x0<256)&(y0>=0)&(y0<256)) ? 1.f : 0.f;
      float m01 = ((x0>=0)&(x0<256)&(y1>=0)&(y1<256)) ? 1.f : 0.f;
      float m10 = ((x1>=0)&(x1<256)&(y0>=0)&(y0<256)) ? 1.f : 0.f;
      float m11 = ((x1>=0)&(x1<256)&(y1>=0)&(y1<256)) ? 1.f : 0.f;
      int x0c = x0 < 0 ? 0 : (x0 > 255 ? 255 : x0);
      int x1c = x1 < 0 ? 0 : (x1 > 255 ? 255 : x1);
      int y0c = y0 < 0 ? 0 : (y0 > 255 ? 255 : y0);
      int y1c = y1 < 0 ? 0 : (y1 > 255 ? 255 : y1);
      int nb = (n<<16);
      float v00 = bf2f(xn[((nb + (y0c<<8) + x0c)<<6) + lane]) * m00;
      float v01 = bf2f(xn[((nb + (y1c<<8) + x0c)<<6) + lane]) * m01;
      float v10 = bf2f(xn[((nb + (y0c<<8) + x1c)<<6) + lane]) * m10;
      float v11 = bf2f(xn[((nb + (y1c<<8) + x1c)<<6) + lane]) * m11;
      float r = (1.f-fx)*((1.f-fy)*v00 + fy*v01) + fx*((1.f-fy)*v10 + fy*v11);
      xs[((rowbase + j)<<6) + lane] = f2bf(r);
    }
  }
}

// ---------------------------------------------------------------------------
// K4: 3x3 conv 64->64 as implicit GEMM, MFMA 16x16x32 bf16.
//     Block: 16x16 px tile (M=256) x Cout=64 (N). K=9 taps x 64c, A-tile
//     (18x18 px, XOR-swizzled) fully LDS-resident; B staged per-ki (24 KB).
//     4 waves, each 4Mx4N 16x16 tiles. Output transposed back to NCHW.
// ---------------------------------------------------------------------------
__global__ __launch_bounds__(256,2) void k_conv2(const unsigned short* __restrict__ xs,
                                                 const unsigned short* __restrict__ Bp,
                                                 const float* __restrict__ b_conv,
                                                 float* __restrict__ out){
  __shared__ unsigned char Al[324*128];     // 41472 B, swizzled
  __shared__ unsigned char Bl[24576];       // 3 taps worth of B frags
  int n = blockIdx.z, i0 = blockIdx.y*16, j0 = blockIdx.x*16;
  int tid = threadIdx.x, w = tid >> 6, l = tid & 63;

  // stage A: pixels (i0-1..i0+16) x (j0-1..j0+16), 8 x 16B chunks each
  const uint4* xs4 = (const uint4*)xs;
  for (int u = tid; u < 324*8; u += 256){
    int p = u >> 3, q = u & 7;
    int rr = p/18, cc = p%18;
    int gi = i0 - 1 + rr, gj = j0 - 1 + cc;
    uint4 v = make_uint4(0u,0u,0u,0u);
    if (gi >= 0 && gi < 256 && gj >= 0 && gj < 256)
      v = xs4[((n<<16) + (gi<<8) + gj)*8 + q];
    int byte = (p*128 + q*16) ^ ((p & 7) << 4);
    *(uint4*)(Al + byte) = v;
  }

  f32x4 zero = {0.f,0.f,0.f,0.f};
  f32x4 acc[4][4];
  #pragma unroll
  for (int m = 0; m < 4; m++)
    #pragma unroll
    for (int t = 0; t < 4; t++) acc[m][t] = zero;

  #pragma unroll
  for (int ki = 0; ki < 3; ki++){
    __syncthreads();                         // prev B consumed (covers A 1st iter)
    { // stage B slice for this ki (1536 uint4)
      const uint4* src = (const uint4*)(Bp + ki*12288);
      uint4* dst = (uint4*)Bl;
      #pragma unroll
      for (int u = 0; u < 6; u++) dst[tid + 256*u] = src[tid + 256*u];
    }
    __syncthreads();
    #pragma unroll
    for (int kj = 0; kj < 3; kj++)
      #pragma unroll
      for (int ch = 0; ch < 2; ch++){
        short8 a[4];
        #pragma unroll
        for (int m = 0; m < 4; m++){
          int p = (w*4 + m + ki)*18 + (l & 15) + kj;
          int byte = (p*128 + ch*64 + ((l >> 4) << 4)) ^ ((p & 7) << 4);
          a[m] = *(const short8*)(Al + byte);
        }
        #pragma unroll
        for (int t = 0; t < 4; t++){
          short8 b = *(const short8*)(Bl + (((kj*2 + ch)*4 + t)*64 + l)*16);
          #pragma unroll
          for (int m = 0; m < 4; m++)
            acc[m][t] = __builtin_amdgcn_mfma_f32_16x16x32_bf16(a[m], b, acc[m][t], 0, 0, 0);
        }
      }
  }

  // epilogue: D lane map: co = t*16 + (l&15), pixel col = (l>>4)*4 + i
  int colp0 = (l >> 4) * 4;
  #pragma unroll
  for (int t = 0; t < 4; t++){
    int co = t*16 + (l & 15);
    float bias = b_conv[co];
    #pragma unroll
    for (int m = 0; m < 4; m++){
      int r = w*4 + m;
      f32x4 v = acc[m][t];
      v[0] += bias; v[1] += bias; v[2] += bias; v[3] += bias;
      *(f32x4*)(&out[(((n*64 + co)<<8) + i0 + r)*256 + j0 + colp0]) = v;
    }
  }
}

// ---------------------------------------------------------------------------
extern "C" void kernel_launch(void* const* d_in, const int* in_sizes, int n_in,
                              void* d_out, int out_size, void* d_ws, size_t ws_size,
                              hipStream_t stream) {
  const float* x      = (const float*)d_in[0];   // [8,64,256,256]
  const float* w_def  = (const float*)d_in[1];   // [2,64,5,5]
  const float* b_def  = (const float*)d_in[2];   // [2]
  const float* w_conv = (const float*)d_in[3];   // [64,64,3,3]
  const float* b_conv = (const float*)d_in[4];   // [64]
  float* out = (float*)d_out;                    // [8,64,256,256]

  // ws layout (138.5 MB): xn bf16 | xs bf16 | gridc f32x2 | Bp bf16
  unsigned char* ws = (unsigned char*)d_ws;
  unsigned short* xn    = (unsigned short*)(ws);
  unsigned short* xsamp = (unsigned short*)(ws + 67108864);
  float2*         gridc = (float2*)(ws + 134217728);
  unsigned short* Bp    = (unsigned short*)(ws + 138412032);

  k_pack_b   <<<144, 256, 0, stream>>>(w_conv, Bp);
  k_transpose<<<dim3(1024, 8), 256, 0, stream>>>(x, xn);
  k_offset   <<<dim3(4, 32, 8), 256, 0, stream>>>(x, w_def, b_def, gridc);
  k_sample   <<<dim3(16, 16, 8), 256, 0, stream>>>(xn, gridc, xsamp);
  k_conv2    <<<dim3(16, 16, 8), 256, 0, stream>>>(xsamp, Bp, b_conv, out);
}

// Round 7
// 435.766 us; speedup vs baseline: 1.2535x; 1.2097x over previous
//
#include <hip/hip_runtime.h>

typedef unsigned int u32;
typedef __attribute__((ext_vector_type(8))) short short8;   // 8 x bf16 MFMA frag
typedef __attribute__((ext_vector_type(4))) float f32x4;

__device__ __forceinline__ unsigned short f2bf(float f){
  u32 u = __builtin_bit_cast(u32, f);
  u = u + 0x7fffu + ((u >> 16) & 1u);           // RNE; inputs are finite
  return (unsigned short)(u >> 16);
}
__device__ __forceinline__ float bf2f(unsigned short h){
  return __builtin_bit_cast(float, ((u32)h) << 16);
}

// ---------------------------------------------------------------------------
// K0: pack w_conv [64][64][3][3] f32 -> bf16 fragments, layout
//     Bp[tap][chunk][t][lane][i]  (tap=ki*3+kj, chunk=K-half, t=co/16)
//     lane l elem i <-> B[k = chunk*32 + (l>>4)*8 + i][co = t*16 + (l&15)]
// ---------------------------------------------------------------------------
__global__ __launch_bounds__(256) void k_pack_b(const float* __restrict__ w_conv,
                                                unsigned short* __restrict__ Bp){
  int idx = blockIdx.x*256 + threadIdx.x;       // 36864 total
  if (idx >= 9*2*4*64*8) return;
  int i    = idx & 7;
  int lane = (idx >> 3) & 63;
  int t    = (idx >> 9) & 3;
  int chunk= (idx >> 11) & 1;
  int tap  = idx >> 12;
  int co = t*16 + (lane & 15);
  int c  = chunk*32 + (lane >> 4)*8 + i;
  int ki = tap/3, kj = tap%3;
  Bp[idx] = f2bf(w_conv[((co*64 + c)*3 + ki)*3 + kj]);
}

// ---------------------------------------------------------------------------
// K1: transpose x NCHW f32 -> NHWC bf16  (64px x 64ch per block)
// ---------------------------------------------------------------------------
__global__ __launch_bounds__(256) void k_transpose(const float* __restrict__ x,
                                                   unsigned short* __restrict__ xn){
  __shared__ float tile[64][65];
  int n = blockIdx.y, pix0 = blockIdx.x*64;
  int tid = threadIdx.x, lane = tid & 63, grp = tid >> 6;
  #pragma unroll
  for (int k = 0; k < 16; k++){
    int c = k*4 + grp;
    tile[c][lane] = x[(n*64 + c)*65536 + pix0 + lane];
  }
  __syncthreads();
  #pragma unroll
  for (int k = 0; k < 16; k++){
    int p = k*4 + grp;
    xn[(n*65536 + pix0 + p)*64 + lane] = f2bf(tile[lane][p]);
  }
}

// ---------------------------------------------------------------------------
// K2: offset conv (fp32, 5x5, pad 2, 64->2) + grid coord build.
//     Full-width tile: 4 output rows x 256 cols. 4 waves x 16 private
//     channels, register acc. Lane owns cols 4l..4l+3; window x[4l-2..4l+5]
//     = 4 aligned float2 loads (OOB-clamped at lanes 0/63, statically
//     masked). Flat 512-block grid with XCD-chunk decode so row-halo
//     re-reads hit XCD-local L2. One 32KB LDS reduce + 1 barrier.
//     Coords stay fp32 (precision-critical: x128 px amplification).
// ---------------------------------------------------------------------------
__global__ __launch_bounds__(256) void k_offset(const float* __restrict__ x,
                                                const float* __restrict__ w_def,
                                                const float* __restrict__ b_def,
                                                float2* __restrict__ gridc){
  __shared__ float red[4][4][2][256];           // 32 KB
  int b = blockIdx.x;                           // 0..511, flat
  int xcd  = b & 7;                             // XCD-chunked decode:
  int w8   = b >> 3;                            //   XCD k <- quads k*8..k*8+7
  int qloc = w8 & 7;                            //   of image n = w8>>3
  int n    = w8 >> 3;
  int i0   = (xcd*8 + qloc)*4;                  // first output row of quad
  int tid = threadIdx.x, l = tid & 63;
  int wv = __builtin_amdgcn_readfirstlane(tid >> 6);   // SGPR wave id

  // static per-lane window geometry (cols 4l-2 .. 4l+5, zeros padding)
  float me0 = (l == 0)  ? 0.f : 1.f;            // cols 4l-2,4l-1 invalid @l=0
  float me1 = (l == 63) ? 0.f : 1.f;            // cols 4l+4,4l+5 invalid @l=63
  int o0 = (l == 0)  ? 0 : -2;                  // OOB-safe clamp (masked anyway)
  int o3 = (l == 63) ? 2 : 4;

  float a0[4][4], a1[4][4];
  #pragma unroll
  for (int s = 0; s < 4; s++)
    #pragma unroll
    for (int q = 0; q < 4; q++){ a0[s][q] = 0.f; a1[s][q] = 0.f; }

  for (int cc = 0; cc < 16; cc++){
    int c = (wv << 4) + cc;
    const float* rp  = x + ((n << 6) + c)*65536 + (l << 2);
    const float* wq0 = w_def + c*25;
    const float* wq1 = w_def + 1600 + c*25;
    float w0[25], w1[25];
    #pragma unroll
    for (int t = 0; t < 25; t++){ w0[t] = wq0[t]; w1[t] = wq1[t]; }

    #pragma unroll
    for (int r = 0; r < 8; r++){                // input rows i0-2 .. i0+5
      int gi = i0 - 2 + r;
      if (gi < 0 || gi > 255) continue;         // wave-uniform
      const float* rr = rp + (gi << 8);
      float2 d0 = *(const float2*)(rr + o0);
      float2 d1 = *(const float2*)(rr);
      float2 d2 = *(const float2*)(rr + 2);
      float2 d3 = *(const float2*)(rr + o3);
      float wd[8];
      wd[0] = d0.x * me0; wd[1] = d0.y * me0;
      wd[2] = d1.x;       wd[3] = d1.y;
      wd[4] = d2.x;       wd[5] = d2.y;
      wd[6] = d3.x * me1; wd[7] = d3.y * me1;
      #pragma unroll
      for (int s = 0; s < 4; s++){
        int ki = r - s;
        if (ki < 0 || ki > 4) continue;         // compile-time after unroll
        #pragma unroll
        for (int q = 0; q < 4; q++)
          #pragma unroll
          for (int kj = 0; kj < 5; kj++){
            a0[s][q] = fmaf(wd[q+kj], w0[ki*5+kj], a0[s][q]);
            a1[s][q] = fmaf(wd[q+kj], w1[ki*5+kj], a1[s][q]);
          }
      }
    }
  }

  #pragma unroll
  for (int s = 0; s < 4; s++)
    #pragma unroll
    for (int q = 0; q < 4; q++){
      red[wv][s][0][(l << 2) + q] = a0[s][q];
      red[wv][s][1][(l << 2) + q] = a1[s][q];
    }
  __syncthreads();

  float bd0 = b_def[0], bd1 = b_def[1];
  #pragma unroll
  for (int v = 0; v < 4; v++){
    int p = tid + (v << 8);                     // 0..1023 = 4 rows x 256 cols
    int s = p >> 8, col = p & 255;
    float s0 = red[0][s][0][col] + red[1][s][0][col] + red[2][s][0][col] + red[3][s][0][col];
    float s1 = red[0][s][1][col] + red[1][s][1][col] + red[2][s][1][col] + red[3][s][1][col];
    int i = i0 + s;
    // grid[...,0] = off0 + linspace(-1,1,H)[i] (ROW), grid[...,1] = off1 + lin[j] (COL)
    float gx = s0 + bd0 + (-1.0f + (2.0f/255.0f)*(float)i);
    float gy = s1 + bd1 + (-1.0f + (2.0f/255.0f)*(float)col);
    float ix = ((gx + 1.0f)*256.0f - 1.0f)*0.5f;   // width coord
    float iy = ((gy + 1.0f)*256.0f - 1.0f)*0.5f;   // height coord
    gridc[((n << 8) + i)*256 + col] = make_float2(ix, iy);
  }
}

// ---------------------------------------------------------------------------
// K3: bilinear sample, zeros padding. One wave = 64 channels of one pixel;
//     each corner = one coalesced 128B bf16 load from NHWC.
// ---------------------------------------------------------------------------
__global__ __launch_bounds__(256) void k_sample(const unsigned short* __restrict__ xn,
                                                const float2* __restrict__ gridc,
                                                unsigned short* __restrict__ xs){
  int n = blockIdx.z, i0 = blockIdx.y*16, j0 = blockIdx.x*16;
  int tid = threadIdx.x, w = tid >> 6, lane = tid & 63;
  for (int s = 0; s < 4; s++){
    int i = i0 + w*4 + s;
    int rowbase = (n<<16) + (i<<8);
    #pragma unroll 2
    for (int j1 = 0; j1 < 16; j1++){
      int j = j0 + j1;
      float2 g = gridc[rowbase + j];
      float ix = g.x, iy = g.y;
      float x0f = floorf(ix), y0f = floorf(iy);
      float fx = ix - x0f, fy = iy - y0f;
      int x0 = (int)x0f, y0 = (int)y0f;
      int x1 = x0 + 1, y1 = y0 + 1;
      float m00 = ((x0>=0)&(x0<256)&(y0>=0)&(y0<256)) ? 1.f : 0.f;
      float m01 = ((x0>=0)&(x0<256)&(y1>=0)&(y1<256)) ? 1.f : 0.f;
      float m10 = ((x1>=0)&(x1<256)&(y0>=0)&(y0<256)) ? 1.f : 0.f;
      float m11 = ((x1>=0)&(x1<256)&(y1>=0)&(y1<256)) ? 1.f : 0.f;
      int x0c = x0 < 0 ? 0 : (x0 > 255 ? 255 : x0);
      int x1c = x1 < 0 ? 0 : (x1 > 255 ? 255 : x1);
      int y0c = y0 < 0 ? 0 : (y0 > 255 ? 255 : y0);
      int y1c = y1 < 0 ? 0 : (y1 > 255 ? 255 : y1);
      int nb = (n<<16);
      float v00 = bf2f(xn[((nb + (y0c<<8) + x0c)<<6) + lane]) * m00;
      float v01 = bf2f(xn[((nb + (y1c<<8) + x0c)<<6) + lane]) * m01;
      float v10 = bf2f(xn[((nb + (y0c<<8) + x1c)<<6) + lane]) * m10;
      float v11 = bf2f(xn[((nb + (y1c<<8) + x1c)<<6) + lane]) * m11;
      float r = (1.f-fx)*((1.f-fy)*v00 + fy*v01) + fx*((1.f-fy)*v10 + fy*v11);
      xs[((rowbase + j)<<6) + lane] = f2bf(r);
    }
  }
}

// ---------------------------------------------------------------------------
// K4: 3x3 conv 64->64 as implicit GEMM, MFMA 16x16x32 bf16.
//     Block: 16x16 px tile (M=256) x Cout=64 (N). K=9 taps x 64c, A-tile
//     (18x18 px, XOR-swizzled) fully LDS-resident; B staged per-ki (24 KB).
//     4 waves, each 4Mx4N 16x16 tiles. Output transposed back to NCHW.
// ---------------------------------------------------------------------------
__global__ __launch_bounds__(256,2) void k_conv2(const unsigned short* __restrict__ xs,
                                                 const unsigned short* __restrict__ Bp,
                                                 const float* __restrict__ b_conv,
                                                 float* __restrict__ out){
  __shared__ unsigned char Al[324*128];     // 41472 B, swizzled
  __shared__ unsigned char Bl[24576];       // 3 taps worth of B frags
  int n = blockIdx.z, i0 = blockIdx.y*16, j0 = blockIdx.x*16;
  int tid = threadIdx.x, w = tid >> 6, l = tid & 63;

  // stage A: pixels (i0-1..i0+16) x (j0-1..j0+16), 8 x 16B chunks each
  const uint4* xs4 = (const uint4*)xs;
  for (int u = tid; u < 324*8; u += 256){
    int p = u >> 3, q = u & 7;
    int rr = p/18, cc = p%18;
    int gi = i0 - 1 + rr, gj = j0 - 1 + cc;
    uint4 v = make_uint4(0u,0u,0u,0u);
    if (gi >= 0 && gi < 256 && gj >= 0 && gj < 256)
      v = xs4[((n<<16) + (gi<<8) + gj)*8 + q];
    int byte = (p*128 + q*16) ^ ((p & 7) << 4);
    *(uint4*)(Al + byte) = v;
  }

  f32x4 zero = {0.f,0.f,0.f,0.f};
  f32x4 acc[4][4];
  #pragma unroll
  for (int m = 0; m < 4; m++)
    #pragma unroll
    for (int t = 0; t < 4; t++) acc[m][t] = zero;

  #pragma unroll
  for (int ki = 0; ki < 3; ki++){
    __syncthreads();                         // prev B consumed (covers A 1st iter)
    { // stage B slice for this ki (1536 uint4)
      const uint4* src = (const uint4*)(Bp + ki*12288);
      uint4* dst = (uint4*)Bl;
      #pragma unroll
      for (int u = 0; u < 6; u++) dst[tid + 256*u] = src[tid + 256*u];
    }
    __syncthreads();
    #pragma unroll
    for (int kj = 0; kj < 3; kj++)
      #pragma unroll
      for (int ch = 0; ch < 2; ch++){
        short8 a[4];
        #pragma unroll
        for (int m = 0; m < 4; m++){
          int p = (w*4 + m + ki)*18 + (l & 15) + kj;
          int byte = (p*128 + ch*64 + ((l >> 4) << 4)) ^ ((p & 7) << 4);
          a[m] = *(const short8*)(Al + byte);
        }
        #pragma unroll
        for (int t = 0; t < 4; t++){
          short8 b = *(const short8*)(Bl + (((kj*2 + ch)*4 + t)*64 + l)*16);
          #pragma unroll
          for (int m = 0; m < 4; m++)
            acc[m][t] = __builtin_amdgcn_mfma_f32_16x16x32_bf16(a[m], b, acc[m][t], 0, 0, 0);
        }
      }
  }

  // epilogue: D lane map: co = t*16 + (l&15), pixel col = (l>>4)*4 + i
  int colp0 = (l >> 4) * 4;
  #pragma unroll
  for (int t = 0; t < 4; t++){
    int co = t*16 + (l & 15);
    float bias = b_conv[co];
    #pragma unroll
    for (int m = 0; m < 4; m++){
      int r = w*4 + m;
      f32x4 v = acc[m][t];
      v[0] += bias; v[1] += bias; v[2] += bias; v[3] += bias;
      *(f32x4*)(&out[(((n*64 + co)<<8) + i0 + r)*256 + j0 + colp0]) = v;
    }
  }
}

// ---------------------------------------------------------------------------
extern "C" void kernel_launch(void* const* d_in, const int* in_sizes, int n_in,
                              void* d_out, int out_size, void* d_ws, size_t ws_size,
                              hipStream_t stream) {
  const float* x      = (const float*)d_in[0];   // [8,64,256,256]
  const float* w_def  = (const float*)d_in[1];   // [2,64,5,5]
  const float* b_def  = (const float*)d_in[2];   // [2]
  const float* w_conv = (const float*)d_in[3];   // [64,64,3,3]
  const float* b_conv = (const float*)d_in[4];   // [64]
  float* out = (float*)d_out;                    // [8,64,256,256]

  // ws layout (138.5 MB): xn bf16 | xs bf16 | gridc f32x2 | Bp bf16
  unsigned char* ws = (unsigned char*)d_ws;
  unsigned short* xn    = (unsigned short*)(ws);
  unsigned short* xsamp = (unsigned short*)(ws + 67108864);
  float2*         gridc = (float2*)(ws + 134217728);
  unsigned short* Bp    = (unsigned short*)(ws + 138412032);

  k_pack_b   <<<144, 256, 0, stream>>>(w_conv, Bp);
  k_transpose<<<dim3(1024, 8), 256, 0, stream>>>(x, xn);
  k_offset   <<<512, 256, 0, stream>>>(x, w_def, b_def, gridc);
  k_sample   <<<dim3(16, 16, 8), 256, 0, stream>>>(xn, gridc, xsamp);
  k_conv2    <<<dim3(16, 16, 8), 256, 0, stream>>>(xsamp, Bp, b_conv, out);
}

// Round 8
// 415.635 us; speedup vs baseline: 1.3142x; 1.0484x over previous
//
#include <hip/hip_runtime.h>

typedef unsigned int u32;
typedef __attribute__((ext_vector_type(8))) short short8;   // 8 x bf16 MFMA frag
typedef __attribute__((ext_vector_type(4))) float f32x4;

__device__ __forceinline__ unsigned short f2bf(float f){
  u32 u = __builtin_bit_cast(u32, f);
  u = u + 0x7fffu + ((u >> 16) & 1u);           // RNE; inputs are finite
  return (unsigned short)(u >> 16);
}
__device__ __forceinline__ float bf2f(unsigned short h){
  return __builtin_bit_cast(float, ((u32)h) << 16);
}

// ---------------------------------------------------------------------------
// K0: pack w_conv [64][64][3][3] f32 -> bf16 fragments, layout
//     Bp[tap][chunk][t][lane][i]  (tap=ki*3+kj, chunk=K-half, t=co/16)
//     lane l elem i <-> B[k = chunk*32 + (l>>4)*8 + i][co = t*16 + (l&15)]
// ---------------------------------------------------------------------------
__global__ __launch_bounds__(256) void k_pack_b(const float* __restrict__ w_conv,
                                                unsigned short* __restrict__ Bp){
  int idx = blockIdx.x*256 + threadIdx.x;       // 36864 total
  if (idx >= 9*2*4*64*8) return;
  int i    = idx & 7;
  int lane = (idx >> 3) & 63;
  int t    = (idx >> 9) & 3;
  int chunk= (idx >> 11) & 1;
  int tap  = idx >> 12;
  int co = t*16 + (lane & 15);
  int c  = chunk*32 + (lane >> 4)*8 + i;
  int ki = tap/3, kj = tap%3;
  Bp[idx] = f2bf(w_conv[((co*64 + c)*3 + ki)*3 + kj]);
}

// ---------------------------------------------------------------------------
// K1: transpose x NCHW f32 -> NHWC bf16  (64px x 64ch per block)
// ---------------------------------------------------------------------------
__global__ __launch_bounds__(256) void k_transpose(const float* __restrict__ x,
                                                   unsigned short* __restrict__ xn){
  __shared__ float tile[64][65];
  int n = blockIdx.y, pix0 = blockIdx.x*64;
  int tid = threadIdx.x, lane = tid & 63, grp = tid >> 6;
  #pragma unroll
  for (int k = 0; k < 16; k++){
    int c = k*4 + grp;
    tile[c][lane] = x[(n*64 + c)*65536 + pix0 + lane];
  }
  __syncthreads();
  #pragma unroll
  for (int k = 0; k < 16; k++){
    int p = k*4 + grp;
    xn[(n*65536 + pix0 + p)*64 + lane] = f2bf(tile[lane][p]);
  }
}

// ---------------------------------------------------------------------------
// K2: offset conv (fp32, 5x5, pad 2, 64->2) + grid coord build.
//     Full-width tile: 4 output rows x 256 cols. 4 waves x 16 private
//     channels, register acc. Lane owns cols 4l..4l+3; window x[4l-2..4l+5]
//     = 4 aligned float2 loads. XCD-chunked flat grid. fp32 (coords
//     amplified x128 -> precision-critical).
// ---------------------------------------------------------------------------
__global__ __launch_bounds__(256) void k_offset(const float* __restrict__ x,
                                                const float* __restrict__ w_def,
                                                const float* __restrict__ b_def,
                                                float2* __restrict__ gridc){
  __shared__ float red[4][4][2][256];           // 32 KB
  int b = blockIdx.x;                           // 0..511, flat
  int xcd  = b & 7;                             // XCD-chunked decode:
  int w8   = b >> 3;                            //   XCD k <- quads k*8..k*8+7
  int qloc = w8 & 7;                            //   of image n = w8>>3
  int n    = w8 >> 3;
  int i0   = (xcd*8 + qloc)*4;                  // first output row of quad
  int tid = threadIdx.x, l = tid & 63;
  int wv = __builtin_amdgcn_readfirstlane(tid >> 6);   // SGPR wave id

  // static per-lane window geometry (cols 4l-2 .. 4l+5, zeros padding)
  float me0 = (l == 0)  ? 0.f : 1.f;            // cols 4l-2,4l-1 invalid @l=0
  float me1 = (l == 63) ? 0.f : 1.f;            // cols 4l+4,4l+5 invalid @l=63
  int o0 = (l == 0)  ? 0 : -2;                  // OOB-safe clamp (masked anyway)
  int o3 = (l == 63) ? 2 : 4;

  float a0[4][4], a1[4][4];
  #pragma unroll
  for (int s = 0; s < 4; s++)
    #pragma unroll
    for (int q = 0; q < 4; q++){ a0[s][q] = 0.f; a1[s][q] = 0.f; }

  for (int cc = 0; cc < 16; cc++){
    int c = (wv << 4) + cc;
    const float* rp  = x + ((n << 6) + c)*65536 + (l << 2);
    const float* wq0 = w_def + c*25;
    const float* wq1 = w_def + 1600 + c*25;
    float w0[25], w1[25];
    #pragma unroll
    for (int t = 0; t < 25; t++){ w0[t] = wq0[t]; w1[t] = wq1[t]; }

    #pragma unroll
    for (int r = 0; r < 8; r++){                // input rows i0-2 .. i0+5
      int gi = i0 - 2 + r;
      if (gi < 0 || gi > 255) continue;         // wave-uniform
      const float* rr = rp + (gi << 8);
      float2 d0 = *(const float2*)(rr + o0);
      float2 d1 = *(const float2*)(rr);
      float2 d2 = *(const float2*)(rr + 2);
      float2 d3 = *(const float2*)(rr + o3);
      float wd[8];
      wd[0] = d0.x * me0; wd[1] = d0.y * me0;
      wd[2] = d1.x;       wd[3] = d1.y;
      wd[4] = d2.x;       wd[5] = d2.y;
      wd[6] = d3.x * me1; wd[7] = d3.y * me1;
      #pragma unroll
      for (int s = 0; s < 4; s++){
        int ki = r - s;
        if (ki < 0 || ki > 4) continue;         // compile-time after unroll
        #pragma unroll
        for (int q = 0; q < 4; q++)
          #pragma unroll
          for (int kj = 0; kj < 5; kj++){
            a0[s][q] = fmaf(wd[q+kj], w0[ki*5+kj], a0[s][q]);
            a1[s][q] = fmaf(wd[q+kj], w1[ki*5+kj], a1[s][q]);
          }
      }
    }
  }

  #pragma unroll
  for (int s = 0; s < 4; s++)
    #pragma unroll
    for (int q = 0; q < 4; q++){
      red[wv][s][0][(l << 2) + q] = a0[s][q];
      red[wv][s][1][(l << 2) + q] = a1[s][q];
    }
  __syncthreads();

  float bd0 = b_def[0], bd1 = b_def[1];
  #pragma unroll
  for (int v = 0; v < 4; v++){
    int p = tid + (v << 8);                     // 0..1023 = 4 rows x 256 cols
    int s = p >> 8, col = p & 255;
    float s0 = red[0][s][0][col] + red[1][s][0][col] + red[2][s][0][col] + red[3][s][0][col];
    float s1 = red[0][s][1][col] + red[1][s][1][col] + red[2][s][1][col] + red[3][s][1][col];
    int i = i0 + s;
    // grid[...,0] = off0 + linspace(-1,1,H)[i] (ROW), grid[...,1] = off1 + lin[j] (COL)
    float gx = s0 + bd0 + (-1.0f + (2.0f/255.0f)*(float)i);
    float gy = s1 + bd1 + (-1.0f + (2.0f/255.0f)*(float)col);
    float ix = ((gx + 1.0f)*256.0f - 1.0f)*0.5f;   // width coord
    float iy = ((gy + 1.0f)*256.0f - 1.0f)*0.5f;   // height coord
    gridc[((n << 8) + i)*256 + col] = make_float2(ix, iy);
  }
}

// ---------------------------------------------------------------------------
// K3 (fused): bilinear-sample + 3x3 conv 64->64 implicit GEMM.
//     A-stage samples the 18x18 halo tile DIRECTLY into swizzled LDS:
//     16 lanes per pixel, ushort4 (4ch) corner gathers from NHWC bf16,
//     lerp in fp32, pack bf16, 8B swizzled LDS write. No xs round-trip.
//     B fragments loaded just-in-time from global (72KB, L1/L2-hot) ->
//     NO in-loop barriers; exactly ONE __syncthreads per block.
//     4 waves x 4Mx4N 16x16x32 MFMA tiles; output NCHW fp32 + bias.
// ---------------------------------------------------------------------------
__global__ __launch_bounds__(256,2) void k_conv2s(const unsigned short* __restrict__ xn,
                                                  const float2* __restrict__ gridc,
                                                  const unsigned short* __restrict__ Bp,
                                                  const float* __restrict__ b_conv,
                                                  float* __restrict__ out){
  __shared__ unsigned char Al[324*128];     // 41472 B, swizzled
  int n = blockIdx.z, i0 = blockIdx.y*16, j0 = blockIdx.x*16;
  int tid = threadIdx.x, w = tid >> 6, l = tid & 63;

  // ---- fused sampling stage: 324 halo pixels, 16 lanes/pixel, 4 ch/lane ----
  int sub   = tid & 15;         // channel quad: ch = sub*4 .. sub*4+3
  int pbase = tid >> 4;         // pixel slot within a 16-pixel pass
  #pragma unroll 2
  for (int pass = 0; pass < 21; ++pass){
    int p = pass*16 + pbase;
    if (p < 324){
      int rr = p/18, cc = p - rr*18;
      int gi = i0 - 1 + rr, gj = j0 - 1 + cc;
      u32 pk0 = 0, pk1 = 0;
      if (gi >= 0 && gi < 256 && gj >= 0 && gj < 256){
        float2 g = gridc[(((n << 8) + gi) << 8) + gj];
        float ix = g.x, iy = g.y;
        float x0f = floorf(ix), y0f = floorf(iy);
        float fx = ix - x0f, fy = iy - y0f;
        int x0 = (int)x0f, y0 = (int)y0f;
        int x1 = x0 + 1, y1 = y0 + 1;
        float m00 = ((x0>=0)&(x0<256)&(y0>=0)&(y0<256)) ? 1.f : 0.f;
        float m01 = ((x0>=0)&(x0<256)&(y1>=0)&(y1<256)) ? 1.f : 0.f;
        float m10 = ((x1>=0)&(x1<256)&(y0>=0)&(y0<256)) ? 1.f : 0.f;
        float m11 = ((x1>=0)&(x1<256)&(y1>=0)&(y1<256)) ? 1.f : 0.f;
        int x0c = x0 < 0 ? 0 : (x0 > 255 ? 255 : x0);
        int x1c = x1 < 0 ? 0 : (x1 > 255 ? 255 : x1);
        int y0c = y0 < 0 ? 0 : (y0 > 255 ? 255 : y0);
        int y1c = y1 < 0 ? 0 : (y1 > 255 ? 255 : y1);
        int nb = n << 16, s4 = sub << 2;
        ushort4 v00 = *(const ushort4*)(xn + (((nb + (y0c<<8) + x0c) << 6) + s4));
        ushort4 v01 = *(const ushort4*)(xn + (((nb + (y1c<<8) + x0c) << 6) + s4));
        ushort4 v10 = *(const ushort4*)(xn + (((nb + (y0c<<8) + x1c) << 6) + s4));
        ushort4 v11 = *(const ushort4*)(xn + (((nb + (y1c<<8) + x1c) << 6) + s4));
        float w00 = (1.f-fx)*(1.f-fy)*m00;
        float w01 = (1.f-fx)*fy*m01;
        float w10 = fx*(1.f-fy)*m10;
        float w11 = fx*fy*m11;
        float r0 = bf2f(v00.x)*w00 + bf2f(v01.x)*w01 + bf2f(v10.x)*w10 + bf2f(v11.x)*w11;
        float r1 = bf2f(v00.y)*w00 + bf2f(v01.y)*w01 + bf2f(v10.y)*w10 + bf2f(v11.y)*w11;
        float r2 = bf2f(v00.z)*w00 + bf2f(v01.z)*w01 + bf2f(v10.z)*w10 + bf2f(v11.z)*w11;
        float r3 = bf2f(v00.w)*w00 + bf2f(v01.w)*w01 + bf2f(v10.w)*w10 + bf2f(v11.w)*w11;
        pk0 = (u32)f2bf(r0) | ((u32)f2bf(r1) << 16);
        pk1 = (u32)f2bf(r2) | ((u32)f2bf(r3) << 16);
      }
      int byte = ((p << 7) + (sub << 3)) ^ ((p & 7) << 4);
      *(uint2*)(Al + byte) = make_uint2(pk0, pk1);
    }
  }

  f32x4 zero = {0.f,0.f,0.f,0.f};
  f32x4 acc[4][4];
  #pragma unroll
  for (int m = 0; m < 4; m++)
    #pragma unroll
    for (int t = 0; t < 4; t++) acc[m][t] = zero;

  __syncthreads();                          // the ONLY barrier

  const short8* bp8 = (const short8*)Bp;    // frag idx = ((tap*2+ch)*4+t)*64+l
  #pragma unroll
  for (int ki = 0; ki < 3; ki++)
    #pragma unroll
    for (int kj = 0; kj < 3; kj++)
      #pragma unroll
      for (int ch = 0; ch < 2; ch++){
        short8 bfr[4];
        #pragma unroll
        for (int t = 0; t < 4; t++)
          bfr[t] = bp8[(((ki*3 + kj)*2 + ch)*4 + t)*64 + l];
        short8 a[4];
        #pragma unroll
        for (int m = 0; m < 4; m++){
          int p = (w*4 + m + ki)*18 + (l & 15) + kj;
          int byte = (p*128 + ch*64 + ((l >> 4) << 4)) ^ ((p & 7) << 4);
          a[m] = *(const short8*)(Al + byte);
        }
        #pragma unroll
        for (int t = 0; t < 4; t++)
          #pragma unroll
          for (int m = 0; m < 4; m++)
            acc[m][t] = __builtin_amdgcn_mfma_f32_16x16x32_bf16(a[m], bfr[t], acc[m][t], 0, 0, 0);
      }

  // epilogue: D lane map: co = t*16 + (l&15), pixel col = (l>>4)*4 + i
  int colp0 = (l >> 4) * 4;
  #pragma unroll
  for (int t = 0; t < 4; t++){
    int co = t*16 + (l & 15);
    float bias = b_conv[co];
    #pragma unroll
    for (int m = 0; m < 4; m++){
      int r = w*4 + m;
      f32x4 v = acc[m][t];
      v[0] += bias; v[1] += bias; v[2] += bias; v[3] += bias;
      *(f32x4*)(&out[(((n*64 + co)<<8) + i0 + r)*256 + j0 + colp0]) = v;
    }
  }
}

// ---------------------------------------------------------------------------
extern "C" void kernel_launch(void* const* d_in, const int* in_sizes, int n_in,
                              void* d_out, int out_size, void* d_ws, size_t ws_size,
                              hipStream_t stream) {
  const float* x      = (const float*)d_in[0];   // [8,64,256,256]
  const float* w_def  = (const float*)d_in[1];   // [2,64,5,5]
  const float* b_def  = (const float*)d_in[2];   // [2]
  const float* w_conv = (const float*)d_in[3];   // [64,64,3,3]
  const float* b_conv = (const float*)d_in[4];   // [64]
  float* out = (float*)d_out;                    // [8,64,256,256]

  // ws layout (~71.4 MB): xn bf16 | gridc f32x2 | Bp bf16
  unsigned char* ws = (unsigned char*)d_ws;
  unsigned short* xn    = (unsigned short*)(ws);
  float2*         gridc = (float2*)(ws + 67108864);
  unsigned short* Bp    = (unsigned short*)(ws + 71303168);

  k_pack_b   <<<144, 256, 0, stream>>>(w_conv, Bp);
  k_transpose<<<dim3(1024, 8), 256, 0, stream>>>(x, xn);
  k_offset   <<<512, 256, 0, stream>>>(x, w_def, b_def, gridc);
  k_conv2s   <<<dim3(16, 16, 8), 256, 0, stream>>>(xn, gridc, Bp, b_conv, out);
}

// Round 9
// 408.117 us; speedup vs baseline: 1.3384x; 1.0184x over previous
//
#include <hip/hip_runtime.h>

typedef unsigned int u32;
typedef __attribute__((ext_vector_type(8))) short short8;   // 8 x bf16 MFMA frag
typedef __attribute__((ext_vector_type(4))) float f32x4;

__device__ __forceinline__ unsigned short f2bf(float f){
  u32 u = __builtin_bit_cast(u32, f);
  u = u + 0x7fffu + ((u >> 16) & 1u);           // RNE; inputs are finite
  return (unsigned short)(u >> 16);
}
__device__ __forceinline__ float bf2f(unsigned short h){
  return __builtin_bit_cast(float, ((u32)h) << 16);
}

// ---------------------------------------------------------------------------
// K0: pack w_conv [64][64][3][3] f32 -> bf16 fragments, layout
//     Bp[tap][chunk][t][lane][i]  (tap=ki*3+kj, chunk=K-half, t=co/16)
//     lane l elem i <-> B[k = chunk*32 + (l>>4)*8 + i][co = t*16 + (l&15)]
// ---------------------------------------------------------------------------
__global__ __launch_bounds__(256) void k_pack_b(const float* __restrict__ w_conv,
                                                unsigned short* __restrict__ Bp){
  int idx = blockIdx.x*256 + threadIdx.x;       // 36864 total
  if (idx >= 9*2*4*64*8) return;
  int i    = idx & 7;
  int lane = (idx >> 3) & 63;
  int t    = (idx >> 9) & 3;
  int chunk= (idx >> 11) & 1;
  int tap  = idx >> 12;
  int co = t*16 + (lane & 15);
  int c  = chunk*32 + (lane >> 4)*8 + i;
  int ki = tap/3, kj = tap%3;
  Bp[idx] = f2bf(w_conv[((co*64 + c)*3 + ki)*3 + kj]);
}

// ---------------------------------------------------------------------------
// K1: transpose x NCHW f32 -> NHWC bf16  (64px x 64ch per block)
// ---------------------------------------------------------------------------
__global__ __launch_bounds__(256) void k_transpose(const float* __restrict__ x,
                                                   unsigned short* __restrict__ xn){
  __shared__ float tile[64][65];
  int n = blockIdx.y, pix0 = blockIdx.x*64;
  int tid = threadIdx.x, lane = tid & 63, grp = tid >> 6;
  #pragma unroll
  for (int k = 0; k < 16; k++){
    int c = k*4 + grp;
    tile[c][lane] = x[(n*64 + c)*65536 + pix0 + lane];
  }
  __syncthreads();
  #pragma unroll
  for (int k = 0; k < 16; k++){
    int p = k*4 + grp;
    xn[(n*65536 + pix0 + p)*64 + lane] = f2bf(tile[lane][p]);
  }
}

// ---------------------------------------------------------------------------
// K2: offset conv (fp32, 5x5, pad 2, 64->2) + grid coord build.
//     Full-width tile: 4 output rows x 256 cols. 4 waves x 16 private
//     channels, register acc. Lane owns cols 4l..4l+3; window x[4l-2..4l+5]
//     = 4 aligned float2 loads. XCD-chunked flat grid. fp32 (coords
//     amplified x128 -> precision-critical).
// ---------------------------------------------------------------------------
__global__ __launch_bounds__(256) void k_offset(const float* __restrict__ x,
                                                const float* __restrict__ w_def,
                                                const float* __restrict__ b_def,
                                                float2* __restrict__ gridc){
  __shared__ float red[4][4][2][256];           // 32 KB
  int b = blockIdx.x;                           // 0..511, flat
  int xcd  = b & 7;                             // XCD-chunked decode:
  int w8   = b >> 3;                            //   XCD k <- quads k*8..k*8+7
  int qloc = w8 & 7;                            //   of image n = w8>>3
  int n    = w8 >> 3;
  int i0   = (xcd*8 + qloc)*4;                  // first output row of quad
  int tid = threadIdx.x, l = tid & 63;
  int wv = __builtin_amdgcn_readfirstlane(tid >> 6);   // SGPR wave id

  // static per-lane window geometry (cols 4l-2 .. 4l+5, zeros padding)
  float me0 = (l == 0)  ? 0.f : 1.f;            // cols 4l-2,4l-1 invalid @l=0
  float me1 = (l == 63) ? 0.f : 1.f;            // cols 4l+4,4l+5 invalid @l=63
  int o0 = (l == 0)  ? 0 : -2;                  // OOB-safe clamp (masked anyway)
  int o3 = (l == 63) ? 2 : 4;

  float a0[4][4], a1[4][4];
  #pragma unroll
  for (int s = 0; s < 4; s++)
    #pragma unroll
    for (int q = 0; q < 4; q++){ a0[s][q] = 0.f; a1[s][q] = 0.f; }

  for (int cc = 0; cc < 16; cc++){
    int c = (wv << 4) + cc;
    const float* rp  = x + ((n << 6) + c)*65536 + (l << 2);
    const float* wq0 = w_def + c*25;
    const float* wq1 = w_def + 1600 + c*25;
    float w0[25], w1[25];
    #pragma unroll
    for (int t = 0; t < 25; t++){ w0[t] = wq0[t]; w1[t] = wq1[t]; }

    #pragma unroll
    for (int r = 0; r < 8; r++){                // input rows i0-2 .. i0+5
      int gi = i0 - 2 + r;
      if (gi < 0 || gi > 255) continue;         // wave-uniform
      const float* rr = rp + (gi << 8);
      float2 d0 = *(const float2*)(rr + o0);
      float2 d1 = *(const float2*)(rr);
      float2 d2 = *(const float2*)(rr + 2);
      float2 d3 = *(const float2*)(rr + o3);
      float wd[8];
      wd[0] = d0.x * me0; wd[1] = d0.y * me0;
      wd[2] = d1.x;       wd[3] = d1.y;
      wd[4] = d2.x;       wd[5] = d2.y;
      wd[6] = d3.x * me1; wd[7] = d3.y * me1;
      #pragma unroll
      for (int s = 0; s < 4; s++){
        int ki = r - s;
        if (ki < 0 || ki > 4) continue;         // compile-time after unroll
        #pragma unroll
        for (int q = 0; q < 4; q++)
          #pragma unroll
          for (int kj = 0; kj < 5; kj++){
            a0[s][q] = fmaf(wd[q+kj], w0[ki*5+kj], a0[s][q]);
            a1[s][q] = fmaf(wd[q+kj], w1[ki*5+kj], a1[s][q]);
          }
      }
    }
  }

  #pragma unroll
  for (int s = 0; s < 4; s++)
    #pragma unroll
    for (int q = 0; q < 4; q++){
      red[wv][s][0][(l << 2) + q] = a0[s][q];
      red[wv][s][1][(l << 2) + q] = a1[s][q];
    }
  __syncthreads();

  float bd0 = b_def[0], bd1 = b_def[1];
  #pragma unroll
  for (int v = 0; v < 4; v++){
    int p = tid + (v << 8);                     // 0..1023 = 4 rows x 256 cols
    int s = p >> 8, col = p & 255;
    float s0 = red[0][s][0][col] + red[1][s][0][col] + red[2][s][0][col] + red[3][s][0][col];
    float s1 = red[0][s][1][col] + red[1][s][1][col] + red[2][s][1][col] + red[3][s][1][col];
    int i = i0 + s;
    // grid[...,0] = off0 + linspace(-1,1,H)[i] (ROW), grid[...,1] = off1 + lin[j] (COL)
    float gx = s0 + bd0 + (-1.0f + (2.0f/255.0f)*(float)i);
    float gy = s1 + bd1 + (-1.0f + (2.0f/255.0f)*(float)col);
    float ix = ((gx + 1.0f)*256.0f - 1.0f)*0.5f;   // width coord
    float iy = ((gy + 1.0f)*256.0f - 1.0f)*0.5f;   // height coord
    gridc[((n << 8) + i)*256 + col] = make_float2(ix, iy);
  }
}

// ---------------------------------------------------------------------------
// K3 (fused): bilinear-sample + 3x3 conv 64->64 implicit GEMM.
//     Sampling is BRANCHLESS (p clamped to 323; dup lanes rewrite identical
//     bytes; halo-OOB folded into weights) and 3-stage software-pipelined:
//       G(P+2): gridc load | S(P+1): addrs+weights, issue 4 gathers | L(P):
//       lerp + swizzled LDS write.  A/B ping-pong named regs, full unroll.
//     B fragments just-in-time from global (L1/L2-hot). ONE barrier total.
//     3 blocks/CU (LDS 3x41.5KB); 4 waves x 4Mx4N 16x16x32 MFMA tiles.
// ---------------------------------------------------------------------------
__global__ __launch_bounds__(256,3) void k_conv2s(const unsigned short* __restrict__ xn,
                                                  const float2* __restrict__ gridc,
                                                  const unsigned short* __restrict__ Bp,
                                                  const float* __restrict__ b_conv,
                                                  float* __restrict__ out){
  __shared__ unsigned char Al[324*128];     // 41472 B, swizzled
  int n = blockIdx.z, i0 = blockIdx.y*16, j0 = blockIdx.x*16;
  int tid = threadIdx.x, w = tid >> 6, l = tid & 63;
  int sub = tid & 15, pbase = tid >> 4;     // 16 lanes/pixel, 4 ch/lane
  const int nb = n << 16, s4 = sub << 2;

#define STAGE_G(P, GQ) { \
  int p_ = (P)*16 + pbase; if (p_ > 323) p_ = 323; \
  int rr_ = p_/18, cc_ = p_ - rr_*18; \
  int gi_ = i0 - 1 + rr_, gj_ = j0 - 1 + cc_; \
  int gic_ = gi_ < 0 ? 0 : (gi_ > 255 ? 255 : gi_); \
  int gjc_ = gj_ < 0 ? 0 : (gj_ > 255 ? 255 : gj_); \
  GQ = gridc[nb + (gic_ << 8) + gjc_]; \
}

#define STAGE_S(P, GQ, WTS, BYTE, C00, C01, C10, C11) { \
  int p_ = (P)*16 + pbase; if (p_ > 323) p_ = 323; \
  int rr_ = p_/18, cc_ = p_ - rr_*18; \
  int gi_ = i0 - 1 + rr_, gj_ = j0 - 1 + cc_; \
  float ok_ = (gi_ >= 0 && gi_ < 256 && gj_ >= 0 && gj_ < 256) ? 1.f : 0.f; \
  float ix_ = GQ.x, iy_ = GQ.y; \
  float x0f_ = floorf(ix_), y0f_ = floorf(iy_); \
  float fx_ = ix_ - x0f_, fy_ = iy_ - y0f_; \
  int x0_ = (int)x0f_, y0_ = (int)y0f_; \
  int x1_ = x0_ + 1, y1_ = y0_ + 1; \
  float m00_ = (((x0_>=0)&(x0_<256)&(y0_>=0)&(y0_<256)) ? 1.f : 0.f) * ok_; \
  float m01_ = (((x0_>=0)&(x0_<256)&(y1_>=0)&(y1_<256)) ? 1.f : 0.f) * ok_; \
  float m10_ = (((x1_>=0)&(x1_<256)&(y0_>=0)&(y0_<256)) ? 1.f : 0.f) * ok_; \
  float m11_ = (((x1_>=0)&(x1_<256)&(y1_>=0)&(y1_<256)) ? 1.f : 0.f) * ok_; \
  int x0c_ = x0_ < 0 ? 0 : (x0_ > 255 ? 255 : x0_); \
  int x1c_ = x1_ < 0 ? 0 : (x1_ > 255 ? 255 : x1_); \
  int y0c_ = y0_ < 0 ? 0 : (y0_ > 255 ? 255 : y0_); \
  int y1c_ = y1_ < 0 ? 0 : (y1_ > 255 ? 255 : y1_); \
  C00 = *(const ushort4*)(xn + (((nb + (y0c_<<8) + x0c_) << 6) + s4)); \
  C01 = *(const ushort4*)(xn + (((nb + (y1c_<<8) + x0c_) << 6) + s4)); \
  C10 = *(const ushort4*)(xn + (((nb + (y0c_<<8) + x1c_) << 6) + s4)); \
  C11 = *(const ushort4*)(xn + (((nb + (y1c_<<8) + x1c_) << 6) + s4)); \
  WTS = make_float4((1.f-fx_)*(1.f-fy_)*m00_, (1.f-fx_)*fy_*m01_, \
                    fx_*(1.f-fy_)*m10_,       fx_*fy_*m11_); \
  BYTE = ((p_ << 7) + (sub << 3)) ^ ((p_ & 7) << 4); \
}

#define STAGE_L(WTS, BYTE, C00, C01, C10, C11) { \
  float r0_ = bf2f(C00.x)*WTS.x + bf2f(C01.x)*WTS.y + bf2f(C10.x)*WTS.z + bf2f(C11.x)*WTS.w; \
  float r1_ = bf2f(C00.y)*WTS.x + bf2f(C01.y)*WTS.y + bf2f(C10.y)*WTS.z + bf2f(C11.y)*WTS.w; \
  float r2_ = bf2f(C00.z)*WTS.x + bf2f(C01.z)*WTS.y + bf2f(C10.z)*WTS.z + bf2f(C11.z)*WTS.w; \
  float r3_ = bf2f(C00.w)*WTS.x + bf2f(C01.w)*WTS.y + bf2f(C10.w)*WTS.z + bf2f(C11.w)*WTS.w; \
  u32 pk0_ = (u32)f2bf(r0_) | ((u32)f2bf(r1_) << 16); \
  u32 pk1_ = (u32)f2bf(r2_) | ((u32)f2bf(r3_) << 16); \
  *(uint2*)(Al + BYTE) = make_uint2(pk0_, pk1_); \
}

  float2 gA, gB; float4 wtsA, wtsB; int byteA, byteB;
  ushort4 a00, a01, a10, a11, b00, b01, b10, b11;
  STAGE_G(0, gA)
  STAGE_G(1, gB)
  STAGE_S(0, gA, wtsA, byteA, a00, a01, a10, a11)
  #pragma unroll
  for (int P = 0; P < 20; P += 2){
    STAGE_S(P+1, gB, wtsB, byteB, b00, b01, b10, b11)
    STAGE_G(P+2, gA)
    STAGE_L(wtsA, byteA, a00, a01, a10, a11)          // pass P
    STAGE_S(P+2, gA, wtsA, byteA, a00, a01, a10, a11)
    STAGE_G(P+3, gB)
    STAGE_L(wtsB, byteB, b00, b01, b10, b11)          // pass P+1
  }
  STAGE_S(21, gB, wtsB, byteB, b00, b01, b10, b11)
  STAGE_L(wtsA, byteA, a00, a01, a10, a11)            // pass 20
  STAGE_L(wtsB, byteB, b00, b01, b10, b11)            // pass 21 (benign dup)

  f32x4 zero = {0.f,0.f,0.f,0.f};
  f32x4 acc[4][4];
  #pragma unroll
  for (int m = 0; m < 4; m++)
    #pragma unroll
    for (int t = 0; t < 4; t++) acc[m][t] = zero;

  __syncthreads();                          // the ONLY barrier

  const short8* bp8 = (const short8*)Bp;    // frag idx = ((tap*2+ch)*4+t)*64+l
  #pragma unroll
  for (int ki = 0; ki < 3; ki++)
    #pragma unroll
    for (int kj = 0; kj < 3; kj++)
      #pragma unroll
      for (int ch = 0; ch < 2; ch++){
        short8 bfr[4];
        #pragma unroll
        for (int t = 0; t < 4; t++)
          bfr[t] = bp8[(((ki*3 + kj)*2 + ch)*4 + t)*64 + l];
        short8 a[4];
        #pragma unroll
        for (int m = 0; m < 4; m++){
          int p = (w*4 + m + ki)*18 + (l & 15) + kj;
          int byte = (p*128 + ch*64 + ((l >> 4) << 4)) ^ ((p & 7) << 4);
          a[m] = *(const short8*)(Al + byte);
        }
        #pragma unroll
        for (int t = 0; t < 4; t++)
          #pragma unroll
          for (int m = 0; m < 4; m++)
            acc[m][t] = __builtin_amdgcn_mfma_f32_16x16x32_bf16(a[m], bfr[t], acc[m][t], 0, 0, 0);
      }

  // epilogue: D lane map: co = t*16 + (l&15), pixel col = (l>>4)*4 + i
  int colp0 = (l >> 4) * 4;
  #pragma unroll
  for (int t = 0; t < 4; t++){
    int co = t*16 + (l & 15);
    float bias = b_conv[co];
    #pragma unroll
    for (int m = 0; m < 4; m++){
      int r = w*4 + m;
      f32x4 v = acc[m][t];
      v[0] += bias; v[1] += bias; v[2] += bias; v[3] += bias;
      *(f32x4*)(&out[(((n*64 + co)<<8) + i0 + r)*256 + j0 + colp0]) = v;
    }
  }
}

// ---------------------------------------------------------------------------
extern "C" void kernel_launch(void* const* d_in, const int* in_sizes, int n_in,
                              void* d_out, int out_size, void* d_ws, size_t ws_size,
                              hipStream_t stream) {
  const float* x      = (const float*)d_in[0];   // [8,64,256,256]
  const float* w_def  = (const float*)d_in[1];   // [2,64,5,5]
  const float* b_def  = (const float*)d_in[2];   // [2]
  const float* w_conv = (const float*)d_in[3];   // [64,64,3,3]
  const float* b_conv = (const float*)d_in[4];   // [64]
  float* out = (float*)d_out;                    // [8,64,256,256]

  // ws layout (~71.4 MB): xn bf16 | gridc f32x2 | Bp bf16
  unsigned char* ws = (unsigned char*)d_ws;
  unsigned short* xn    = (unsigned short*)(ws);
  float2*         gridc = (float2*)(ws + 67108864);
  unsigned short* Bp    = (unsigned short*)(ws + 71303168);

  k_pack_b   <<<144, 256, 0, stream>>>(w_conv, Bp);
  k_transpose<<<dim3(1024, 8), 256, 0, stream>>>(x, xn);
  k_offset   <<<512, 256, 0, stream>>>(x, w_def, b_def, gridc);
  k_conv2s   <<<dim3(16, 16, 8), 256, 0, stream>>>(xn, gridc, Bp, b_conv, out);
}

// Round 13
// 391.954 us; speedup vs baseline: 1.3936x; 1.0412x over previous
//
#include <hip/hip_runtime.h>

typedef unsigned int u32;
typedef __attribute__((ext_vector_type(8))) short short8;   // 8 x bf16 MFMA frag
typedef __attribute__((ext_vector_type(4))) float f32x4;

__device__ __forceinline__ unsigned short f2bf(float f){
  u32 u = __builtin_bit_cast(u32, f);
  u = u + 0x7fffu + ((u >> 16) & 1u);           // RNE; inputs are finite
  return (unsigned short)(u >> 16);
}
__device__ __forceinline__ float bf2f(unsigned short h){
  return __builtin_bit_cast(float, ((u32)h) << 16);
}

// ---------------------------------------------------------------------------
// K0: pack w_conv [64][64][3][3] f32 -> bf16 fragments, layout
//     Bp[tap][chunk][t][lane][i]  (tap=ki*3+kj, chunk=K-half, t=co/16)
//     lane l elem i <-> B[k = chunk*32 + (l>>4)*8 + i][co = t*16 + (l&15)]
// ---------------------------------------------------------------------------
__global__ __launch_bounds__(256) void k_pack_b(const float* __restrict__ w_conv,
                                                unsigned short* __restrict__ Bp){
  int idx = blockIdx.x*256 + threadIdx.x;       // 36864 total
  if (idx >= 9*2*4*64*8) return;
  int i    = idx & 7;
  int lane = (idx >> 3) & 63;
  int t    = (idx >> 9) & 3;
  int chunk= (idx >> 11) & 1;
  int tap  = idx >> 12;
  int co = t*16 + (lane & 15);
  int c  = chunk*32 + (lane >> 4)*8 + i;
  int ki = tap/3, kj = tap%3;
  Bp[idx] = f2bf(w_conv[((co*64 + c)*3 + ki)*3 + kj]);
}

// ---------------------------------------------------------------------------
// K1: transpose x NCHW f32 -> NHWC bf16  (64px x 64ch per block)
// ---------------------------------------------------------------------------
__global__ __launch_bounds__(256) void k_transpose(const float* __restrict__ x,
                                                   unsigned short* __restrict__ xn){
  __shared__ float tile[64][65];
  int n = blockIdx.y, pix0 = blockIdx.x*64;
  int tid = threadIdx.x, lane = tid & 63, grp = tid >> 6;
  #pragma unroll
  for (int k = 0; k < 16; k++){
    int c = k*4 + grp;
    tile[c][lane] = x[(n*64 + c)*65536 + pix0 + lane];
  }
  __syncthreads();
  #pragma unroll
  for (int k = 0; k < 16; k++){
    int p = k*4 + grp;
    xn[(n*65536 + pix0 + p)*64 + lane] = f2bf(tile[lane][p]);
  }
}

// ---------------------------------------------------------------------------
// K2: offset conv (fp32, 5x5, pad 2, 64->2) + grid coord build.
//     2 output rows x 256 cols per block -> 1024 blocks (4/CU, 16 waves/CU;
//     the 512-block version starved at 2 blocks/CU). 4 waves x 16 private
//     channels, register acc; lane owns cols 4l..4l+3 via 4 float2 loads.
//     XCD-chunked flat decode keeps row-halo re-reads L2-local.
//     fp32 throughout (coords amplified x128 -> precision-critical).
// ---------------------------------------------------------------------------
__global__ __launch_bounds__(256) void k_offset(const float* __restrict__ x,
                                                const float* __restrict__ w_def,
                                                const float* __restrict__ b_def,
                                                float2* __restrict__ gridc){
  __shared__ float red[4][2][2][256];           // 16 KB
  int b = blockIdx.x;                           // 0..1023, flat
  int xcd  = b & 7;                             // XCD-chunked decode:
  int w8   = b >> 3;                            //   XCD k <- pairs k*16..k*16+15
  int qloc = w8 & 15;                           //   of image n = w8>>4
  int n    = w8 >> 4;
  int i0   = (xcd*16 + qloc)*2;                 // first output row of pair
  int tid = threadIdx.x, l = tid & 63;
  int wv = __builtin_amdgcn_readfirstlane(tid >> 6);   // SGPR wave id

  // static per-lane window geometry (cols 4l-2 .. 4l+5, zeros padding)
  float me0 = (l == 0)  ? 0.f : 1.f;            // cols 4l-2,4l-1 invalid @l=0
  float me1 = (l == 63) ? 0.f : 1.f;            // cols 4l+4,4l+5 invalid @l=63
  int o0 = (l == 0)  ? 0 : -2;                  // OOB-safe clamp (masked anyway)
  int o3 = (l == 63) ? 2 : 4;

  float a0[2][4], a1[2][4];
  #pragma unroll
  for (int s = 0; s < 2; s++)
    #pragma unroll
    for (int q = 0; q < 4; q++){ a0[s][q] = 0.f; a1[s][q] = 0.f; }

  for (int cc = 0; cc < 16; cc++){
    int c = (wv << 4) + cc;
    const float* rp  = x + ((n << 6) + c)*65536 + (l << 2);
    const float* wq0 = w_def + c*25;
    const float* wq1 = w_def + 1600 + c*25;
    float w0[25], w1[25];
    #pragma unroll
    for (int t = 0; t < 25; t++){ w0[t] = wq0[t]; w1[t] = wq1[t]; }

    #pragma unroll
    for (int r = 0; r < 6; r++){                // input rows i0-2 .. i0+3
      int gi = i0 - 2 + r;
      if (gi < 0 || gi > 255) continue;         // wave-uniform
      const float* rr = rp + (gi << 8);
      float2 d0 = *(const float2*)(rr + o0);
      float2 d1 = *(const float2*)(rr);
      float2 d2 = *(const float2*)(rr + 2);
      float2 d3 = *(const float2*)(rr + o3);
      float wd[8];
      wd[0] = d0.x * me0; wd[1] = d0.y * me0;
      wd[2] = d1.x;       wd[3] = d1.y;
      wd[4] = d2.x;       wd[5] = d2.y;
      wd[6] = d3.x * me1; wd[7] = d3.y * me1;
      #pragma unroll
      for (int s = 0; s < 2; s++){
        int ki = r - s;
        if (ki < 0 || ki > 4) continue;         // compile-time after unroll
        #pragma unroll
        for (int q = 0; q < 4; q++)
          #pragma unroll
          for (int kj = 0; kj < 5; kj++){
            a0[s][q] = fmaf(wd[q+kj], w0[ki*5+kj], a0[s][q]);
            a1[s][q] = fmaf(wd[q+kj], w1[ki*5+kj], a1[s][q]);
          }
      }
    }
  }

  #pragma unroll
  for (int s = 0; s < 2; s++)
    #pragma unroll
    for (int q = 0; q < 4; q++){
      red[wv][s][0][(l << 2) + q] = a0[s][q];
      red[wv][s][1][(l << 2) + q] = a1[s][q];
    }
  __syncthreads();

  float bd0 = b_def[0], bd1 = b_def[1];
  #pragma unroll
  for (int v = 0; v < 2; v++){
    int p = tid + (v << 8);                     // 0..511 = 2 rows x 256 cols
    int s = p >> 8, col = p & 255;
    float s0 = red[0][s][0][col] + red[1][s][0][col] + red[2][s][0][col] + red[3][s][0][col];
    float s1 = red[0][s][1][col] + red[1][s][1][col] + red[2][s][1][col] + red[3][s][1][col];
    int i = i0 + s;
    // grid[...,0] = off0 + linspace(-1,1,H)[i] (ROW), grid[...,1] = off1 + lin[j] (COL)
    float gx = s0 + bd0 + (-1.0f + (2.0f/255.0f)*(float)i);
    float gy = s1 + bd1 + (-1.0f + (2.0f/255.0f)*(float)col);
    float ix = ((gx + 1.0f)*256.0f - 1.0f)*0.5f;   // width coord
    float iy = ((gy + 1.0f)*256.0f - 1.0f)*0.5f;   // height coord
    gridc[((n << 8) + i)*256 + col] = make_float2(ix, iy);
  }
}

// ---------------------------------------------------------------------------
// K3 (fused): bilinear-sample + 3x3 conv 64->64 implicit GEMM.
//     512 threads / 8 waves per block, SAME 41.5KB LDS tile -> up to
//     24 waves/CU (was 9.6): TLP hides the random gather latency.
//     Sampling: 32 px/pass x 11 passes, branchless, 2-deep ping-pong
//     (G: gridc load | S: addrs+weights+4 gathers | L: lerp+LDS write).
//     MFMA: wave w owns pixel rows {2w,2w+1} x all 64 couts, acc[2][4];
//     B frags just-in-time from global (L1-hot). ONE barrier total.
// ---------------------------------------------------------------------------
__global__ __launch_bounds__(512,6) void k_conv2s(const unsigned short* __restrict__ xn,
                                                  const float2* __restrict__ gridc,
                                                  const unsigned short* __restrict__ Bp,
                                                  const float* __restrict__ b_conv,
                                                  float* __restrict__ out){
  __shared__ unsigned char Al[324*128];     // 41472 B, swizzled
  int n = blockIdx.z, i0 = blockIdx.y*16, j0 = blockIdx.x*16;
  int tid = threadIdx.x, w = tid >> 6, l = tid & 63;
  int sub = tid & 15, pbase = tid >> 4;     // 16 lanes/pixel, 32 px/pass
  const int nb = n << 16, s4 = sub << 2;

#define STAGE_G(P, GQ) { \
  int p_ = (P)*32 + pbase; if (p_ > 323) p_ = 323; \
  int rr_ = p_/18, cc_ = p_ - rr_*18; \
  int gi_ = i0 - 1 + rr_, gj_ = j0 - 1 + cc_; \
  int gic_ = gi_ < 0 ? 0 : (gi_ > 255 ? 255 : gi_); \
  int gjc_ = gj_ < 0 ? 0 : (gj_ > 255 ? 255 : gj_); \
  GQ = gridc[nb + (gic_ << 8) + gjc_]; \
}

#define STAGE_S(P, GQ, WTS, BYTE, C00, C01, C10, C11) { \
  int p_ = (P)*32 + pbase; if (p_ > 323) p_ = 323; \
  int rr_ = p_/18, cc_ = p_ - rr_*18; \
  int gi_ = i0 - 1 + rr_, gj_ = j0 - 1 + cc_; \
  float ok_ = (gi_ >= 0 && gi_ < 256 && gj_ >= 0 && gj_ < 256) ? 1.f : 0.f; \
  float ix_ = GQ.x, iy_ = GQ.y; \
  float x0f_ = floorf(ix_), y0f_ = floorf(iy_); \
  float fx_ = ix_ - x0f_, fy_ = iy_ - y0f_; \
  int x0_ = (int)x0f_, y0_ = (int)y0f_; \
  int x1_ = x0_ + 1, y1_ = y0_ + 1; \
  float m00_ = (((x0_>=0)&(x0_<256)&(y0_>=0)&(y0_<256)) ? 1.f : 0.f) * ok_; \
  float m01_ = (((x0_>=0)&(x0_<256)&(y1_>=0)&(y1_<256)) ? 1.f : 0.f) * ok_; \
  float m10_ = (((x1_>=0)&(x1_<256)&(y0_>=0)&(y0_<256)) ? 1.f : 0.f) * ok_; \
  float m11_ = (((x1_>=0)&(x1_<256)&(y1_>=0)&(y1_<256)) ? 1.f : 0.f) * ok_; \
  int x0c_ = x0_ < 0 ? 0 : (x0_ > 255 ? 255 : x0_); \
  int x1c_ = x1_ < 0 ? 0 : (x1_ > 255 ? 255 : x1_); \
  int y0c_ = y0_ < 0 ? 0 : (y0_ > 255 ? 255 : y0_); \
  int y1c_ = y1_ < 0 ? 0 : (y1_ > 255 ? 255 : y1_); \
  C00 = *(const ushort4*)(xn + (((nb + (y0c_<<8) + x0c_) << 6) + s4)); \
  C01 = *(const ushort4*)(xn + (((nb + (y1c_<<8) + x0c_) << 6) + s4)); \
  C10 = *(const ushort4*)(xn + (((nb + (y0c_<<8) + x1c_) << 6) + s4)); \
  C11 = *(const ushort4*)(xn + (((nb + (y1c_<<8) + x1c_) << 6) + s4)); \
  WTS = make_float4((1.f-fx_)*(1.f-fy_)*m00_, (1.f-fx_)*fy_*m01_, \
                    fx_*(1.f-fy_)*m10_,       fx_*fy_*m11_); \
  BYTE = ((p_ << 7) + (sub << 3)) ^ ((p_ & 7) << 4); \
}

#define STAGE_L(WTS, BYTE, C00, C01, C10, C11) { \
  float r0_ = bf2f(C00.x)*WTS.x + bf2f(C01.x)*WTS.y + bf2f(C10.x)*WTS.z + bf2f(C11.x)*WTS.w; \
  float r1_ = bf2f(C00.y)*WTS.x + bf2f(C01.y)*WTS.y + bf2f(C10.y)*WTS.z + bf2f(C11.y)*WTS.w; \
  float r2_ = bf2f(C00.z)*WTS.x + bf2f(C01.z)*WTS.y + bf2f(C10.z)*WTS.z + bf2f(C11.z)*WTS.w; \
  float r3_ = bf2f(C00.w)*WTS.x + bf2f(C01.w)*WTS.y + bf2f(C10.w)*WTS.z + bf2f(C11.w)*WTS.w; \
  u32 pk0_ = (u32)f2bf(r0_) | ((u32)f2bf(r1_) << 16); \
  u32 pk1_ = (u32)f2bf(r2_) | ((u32)f2bf(r3_) << 16); \
  *(uint2*)(Al + BYTE) = make_uint2(pk0_, pk1_); \
}

  float2 gA, gB; float4 wtsA, wtsB; int byteA, byteB;
  ushort4 a00, a01, a10, a11, b00, b01, b10, b11;
  STAGE_G(0, gA)
  STAGE_G(1, gB)
  STAGE_S(0, gA, wtsA, byteA, a00, a01, a10, a11)
  #pragma unroll
  for (int P = 0; P < 10; P += 2){
    STAGE_S(P+1, gB, wtsB, byteB, b00, b01, b10, b11)
    STAGE_G(P+2, gA)
    STAGE_L(wtsA, byteA, a00, a01, a10, a11)          // pass P
    STAGE_S(P+2, gA, wtsA, byteA, a00, a01, a10, a11)
    STAGE_G(P+3, gB)
    STAGE_L(wtsB, byteB, b00, b01, b10, b11)          // pass P+1
  }
  STAGE_L(wtsA, byteA, a00, a01, a10, a11)            // pass 10

  f32x4 zero = {0.f,0.f,0.f,0.f};
  f32x4 acc[2][4];
  #pragma unroll
  for (int m = 0; m < 2; m++)
    #pragma unroll
    for (int t = 0; t < 4; t++) acc[m][t] = zero;

  __syncthreads();                          // the ONLY barrier

  const short8* bp8 = (const short8*)Bp;    // frag idx = ((tap*2+ch)*4+t)*64+l
  #pragma unroll
  for (int ki = 0; ki < 3; ki++)
    #pragma unroll
    for (int kj = 0; kj < 3; kj++)
      #pragma unroll
      for (int ch = 0; ch < 2; ch++){
        short8 bfr[4];
        #pragma unroll
        for (int t = 0; t < 4; t++)
          bfr[t] = bp8[(((ki*3 + kj)*2 + ch)*4 + t)*64 + l];
        short8 a[2];
        #pragma unroll
        for (int m = 0; m < 2; m++){
          int p = (w*2 + m + ki)*18 + (l & 15) + kj;
          int byte = (p*128 + ch*64 + ((l >> 4) << 4)) ^ ((p & 7) << 4);
          a[m] = *(const short8*)(Al + byte);
        }
        #pragma unroll
        for (int t = 0; t < 4; t++)
          #pragma unroll
          for (int m = 0; m < 2; m++)
            acc[m][t] = __builtin_amdgcn_mfma_f32_16x16x32_bf16(a[m], bfr[t], acc[m][t], 0, 0, 0);
      }

  // epilogue: D lane map: co = t*16 + (l&15), pixel col = (l>>4)*4 + i
  int colp0 = (l >> 4) * 4;
  #pragma unroll
  for (int t = 0; t < 4; t++){
    int co = t*16 + (l & 15);
    float bias = b_conv[co];
    #pragma unroll
    for (int m = 0; m < 2; m++){
      int r = w*2 + m;
      f32x4 v = acc[m][t];
      v[0] += bias; v[1] += bias; v[2] += bias; v[3] += bias;
      *(f32x4*)(&out[(((n*64 + co)<<8) + i0 + r)*256 + j0 + colp0]) = v;
    }
  }
}

// ---------------------------------------------------------------------------
extern "C" void kernel_launch(void* const* d_in, const int* in_sizes, int n_in,
                              void* d_out, int out_size, void* d_ws, size_t ws_size,
                              hipStream_t stream) {
  const float* x      = (const float*)d_in[0];   // [8,64,256,256]
  const float* w_def  = (const float*)d_in[1];   // [2,64,5,5]
  const float* b_def  = (const float*)d_in[2];   // [2]
  const float* w_conv = (const float*)d_in[3];   // [64,64,3,3]
  const float* b_conv = (const float*)d_in[4];   // [64]
  float* out = (float*)d_out;                    // [8,64,256,256]

  // ws layout (~71.4 MB): xn bf16 | gridc f32x2 | Bp bf16
  unsigned char* ws = (unsigned char*)d_ws;
  unsigned short* xn    = (unsigned short*)(ws);
  float2*         gridc = (float2*)(ws + 67108864);
  unsigned short* Bp    = (unsigned short*)(ws + 71303168);

  k_pack_b   <<<144, 256, 0, stream>>>(w_conv, Bp);
  k_transpose<<<dim3(1024, 8), 256, 0, stream>>>(x, xn);
  k_offset   <<<1024, 256, 0, stream>>>(x, w_def, b_def, gridc);
  k_conv2s   <<<dim3(16, 16, 8), 512, 0, stream>>>(xn, gridc, Bp, b_conv, out);
}